// Round 3
// baseline (753.490 us; speedup 1.0000x reference)
//
#include <hip/hip_runtime.h>
#include <float.h>

// EdgeConv decomposition (all fp32 I/O per the reference):
//   out[b,o,n] = P[b,n,o] + max_{j<20} Q[b, idx[b,n,j], o]
//   P = (W1-W2)^T x + b ; Q = W2^T x
//   idx = 20 smallest of score[m] = sq[m] - 2*x_n.x_m  (m != n; sq_n is row-constant)
// Fused scores+topk (no materialized S). ws: idx | sq | Q  (~10.75 MiB)

#define BB 8
#define FF 64
#define NN 4096
#define KK 20

// ---------------- prep: sq[b][n], Q[b][n][o] ----------------
__global__ void __launch_bounds__(256) prep_kernel(
    const float* __restrict__ x, const float* __restrict__ W,
    float* __restrict__ sq, float* __restrict__ Q)
{
  __shared__ float xs[64][65];
  __shared__ float w2[64][65];
  int t = threadIdx.x;
  int b = blockIdx.x >> 6;
  int n0 = (blockIdx.x & 63) << 6;
  const float* xb = x + (size_t)b * FF * NN;

  int nl = t & 63, fq = t >> 6;
  #pragma unroll
  for (int i = 0; i < 16; ++i) {
    int f = fq + i * 4;
    xs[f][nl] = xb[(size_t)f * NN + n0 + nl];
  }
  #pragma unroll
  for (int i = 0; i < 16; ++i) {
    int id = i * 256 + t;            // 0..4095
    int o = id >> 6, f = id & 63;
    w2[o][f] = W[o * 128 + 64 + f];  // W2
  }
  __syncthreads();

  if (t < 64) {
    float s = 0.f;
    #pragma unroll
    for (int f = 0; f < FF; ++f) { float v = xs[f][t]; s += v * v; }
    sq[b * NN + n0 + t] = s;
  }
  int o = t & 63, g = t >> 6;
  for (int i = 0; i < 16; ++i) {
    int r = g + i * 4;
    float acc = 0.f;
    #pragma unroll
    for (int f = 0; f < FF; ++f) acc += w2[o][f] * xs[f][r];
    Q[((size_t)b * NN + n0 + r) * FF + o] = acc;
  }
}

// ---------------- fused scores + top-20 ----------------
__global__ void __launch_bounds__(256) knn_kernel(
    const float* __restrict__ x, const float* __restrict__ sq,
    int* __restrict__ idxOut)
{
  __shared__ __align__(16) float As[64][68];
  __shared__ __align__(16) float Bs[64][68];
  __shared__ float sc[64][65];
  __shared__ float sqm[64];
  int t = threadIdx.x;
  int b = blockIdx.x >> 6;
  int n0 = (blockIdx.x & 63) << 6;
  const float* xb = x + (size_t)b * FF * NN;

  int c4 = t & 15, fr = t >> 4;     // float4 column, f-row group
  #pragma unroll
  for (int i = 0; i < 4; ++i) {
    int f = fr + 16 * i;
    *(float4*)&As[f][4 * c4] = *(const float4*)&xb[(size_t)f * NN + n0 + 4 * c4];
  }

  int lane = t & 63, w = t >> 6;
  int tc = t & 15, tr = t >> 4;

  // running top-20 per row, element at list position `lane` (lane<20); 16 rows/wave
  float vals[16]; int ids[16];
  #pragma unroll
  for (int r = 0; r < 16; ++r) { vals[r] = FLT_MAX; ids[r] = 0; }

  for (int mt = 0; mt < 64; ++mt) {
    int m0 = mt << 6;
    __syncthreads();                 // prior iter done reading Bs/sc
    #pragma unroll
    for (int i = 0; i < 4; ++i) {
      int f = fr + 16 * i;
      *(float4*)&Bs[f][4 * c4] = *(const float4*)&xb[(size_t)f * NN + m0 + 4 * c4];
    }
    if (t < 64) sqm[t] = sq[b * NN + m0 + t];
    __syncthreads();

    float acc[4][4];
    #pragma unroll
    for (int i = 0; i < 4; ++i)
      #pragma unroll
      for (int j = 0; j < 4; ++j) acc[i][j] = 0.f;

    for (int f = 0; f < 64; ++f) {
      float4 av = *(const float4*)&As[f][tr * 4];
      float4 bv = *(const float4*)&Bs[f][tc * 4];
      float a4[4] = { av.x, av.y, av.z, av.w };
      float b4[4] = { bv.x, bv.y, bv.z, bv.w };
      #pragma unroll
      for (int i = 0; i < 4; ++i)
        #pragma unroll
        for (int j = 0; j < 4; ++j) acc[i][j] += a4[i] * b4[j];
    }
    #pragma unroll
    for (int i = 0; i < 4; ++i)
      #pragma unroll
      for (int j = 0; j < 4; ++j)
        sc[tr * 4 + i][tc * 4 + j] = sqm[tc * 4 + j] - 2.f * acc[i][j];
    __syncthreads();

    // wave w owns local rows 16w..16w+15 (exactly the sc rows it wrote)
    #pragma unroll
    for (int r = 0; r < 16; ++r) {
      int n = n0 + w * 16 + r;
      float cand = sc[w * 16 + r][lane];
      if (m0 + lane == n) cand = FLT_MAX;          // self-exclusion
      float kth = __shfl(vals[r], 19);
      unsigned long long mask = __ballot(cand < kth);
      while (mask) {
        int s = __ffsll(mask) - 1;
        mask &= mask - 1;
        float cv = __shfl(cand, s);
        kth = __shfl(vals[r], 19);
        if (cv < kth) {
          int ci = m0 + s;
          float pv = __shfl_up(vals[r], 1);
          int   pi = __shfl_up(ids[r], 1);
          bool shift = (lane > 0) && (pv > cv);
          if (lane < KK && vals[r] > cv) {
            vals[r] = shift ? pv : cv;
            ids[r]  = shift ? pi : ci;
          }
        }
      }
    }
  }

  if (lane < KK) {
    #pragma unroll
    for (int r = 0; r < 16; ++r)
      idxOut[((size_t)b * NN + n0 + w * 16 + r) * KK + lane] = ids[r];
  }
}

// ---------------- gather: out[b,o,n] = P + max_j Q[nbr_j] ----------------
__global__ void __launch_bounds__(256) gather_kernel(
    const float* __restrict__ x, const float* __restrict__ W,
    const float* __restrict__ bias,
    const float* __restrict__ Q, const int* __restrict__ idxIn,
    float* __restrict__ out)
{
  __shared__ float xs[64][65];
  __shared__ float wp[64][65];
  __shared__ float ot[64][65];
  __shared__ float bs[64];
  int t = threadIdx.x;
  int b = blockIdx.x >> 6;
  int n0 = (blockIdx.x & 63) << 6;
  const float* xb = x + (size_t)b * FF * NN;

  int nl0 = t & 63, fq = t >> 6;
  #pragma unroll
  for (int i = 0; i < 16; ++i) {
    int f = fq + i * 4;
    xs[f][nl0] = xb[(size_t)f * NN + n0 + nl0];
  }
  #pragma unroll
  for (int i = 0; i < 16; ++i) {
    int id = i * 256 + t;            // 0..4095
    int o = id >> 6, f = id & 63;
    wp[o][f] = W[o * 128 + f] - W[o * 128 + 64 + f];   // W1 - W2
  }
  if (t < 64) bs[t] = bias[t];
  __syncthreads();

  int o = t & 63, g = t >> 6;
  for (int i = 0; i < 16; ++i) {
    int nl = g + i * 4;
    int n = n0 + nl;
    float p = bs[o];
    #pragma unroll
    for (int f = 0; f < FF; ++f) p += wp[o][f] * xs[f][nl];
    const int* ip = idxIn + ((size_t)b * NN + n) * KK;
    float m = -FLT_MAX;
    #pragma unroll
    for (int j = 0; j < KK; ++j) {
      int nb = ip[j];                                   // wave-uniform
      m = fmaxf(m, Q[((size_t)b * NN + nb) * FF + o]);  // 256B coalesced
    }
    ot[nl][o] = p + m;
  }
  __syncthreads();
  for (int i = 0; i < 16; ++i) {
    int o2 = g + i * 4;
    int nl = t & 63;
    out[((size_t)b * FF + o2) * NN + n0 + nl] = ot[nl][o2];
  }
}

extern "C" void kernel_launch(void* const* d_in, const int* in_sizes, int n_in,
                              void* d_out, int out_size, void* d_ws, size_t ws_size,
                              hipStream_t stream)
{
  const float* x    = (const float*)d_in[0];
  const float* W    = (const float*)d_in[1];
  const float* bias = (const float*)d_in[2];
  float* out = (float*)d_out;

  int*   idxb = (int*)d_ws;                             // 8*4096*20 ints
  float* sq   = (float*)(idxb + (size_t)BB * NN * KK);  // 8*4096
  float* Q    = sq + (size_t)BB * NN;                   // 8*4096*64

  prep_kernel<<<BB * (NN / 64), 256, 0, stream>>>(x, W, sq, Q);
  knn_kernel<<<BB * (NN / 64), 256, 0, stream>>>(x, sq, idxb);
  gather_kernel<<<BB * (NN / 64), 256, 0, stream>>>(x, W, bias, Q, idxb, out);
}